// Round 10
// baseline (328.426 us; speedup 1.0000x reference)
//
#include <hip/hip_runtime.h>
#include <hip/hip_bf16.h>

// ConvCls partial-FC 1x1-conv classifier — SINGLE fused kernel.
// out[b,u,hw] = sum_c x[b,c,hw] * W[sorted[u], c] + bias[sorted[u]]
// Flattened GEMM: C[m,u], m = b*49+hw, M = 25088 = 128*196 exact.
// fp32 via bf16 hi/lo split, 3 MFMA passes (hh + hl + lh), fp32 accumulate.
#define CIN    512
#define BATCH  512
#define HW     49
#define UDIM   512
#define MTOT   (BATCH * HW)     // 25088
#define MT     128              // m-tile per block
#define NMB    (MTOT / MT)      // 196
#define UHALF  256              // u per block
#define KT     16               // K per pipeline step
#define NSTEP  (CIN / KT)       // 32
#define NBLK   (NMB * 2)        // 392 = 8*49 (bijective XCD swizzle)

typedef short  bf16x8 __attribute__((ext_vector_type(8)));
typedef short  s16x4  __attribute__((ext_vector_type(4)));
typedef short  s16x8  __attribute__((ext_vector_type(8)));
typedef float  f32x4  __attribute__((ext_vector_type(4)));
typedef float  f32x16 __attribute__((ext_vector_type(16)));

#define MFMA32(A, B, C) __builtin_amdgcn_mfma_f32_32x32x16_bf16((A), (B), (C), 0, 0, 0)

// fp32 -> bf16 hi/lo split (RNE via bit trick; finite inputs)
__device__ __forceinline__ void split2(float v, unsigned short& h, unsigned short& l) {
  unsigned int b  = __float_as_uint(v);
  unsigned int hb = (b + 0x7FFFu + ((b >> 16) & 1u)) >> 16;
  float hf        = __uint_as_float(hb << 16);
  unsigned int lb = __float_as_uint(v - hf);
  h = (unsigned short)hb;
  l = (unsigned short)((lb + 0x7FFFu + ((lb >> 16) & 1u)) >> 16);
}

__device__ __forceinline__ f32x16 zero16() {
  f32x16 r;
#pragma unroll
  for (int i = 0; i < 16; ++i) r[i] = 0.f;
  return r;
}

__global__ __launch_bounds__(512, 4) void convcls_fused(
    const float* __restrict__ x,
    const int*   __restrict__ labels,
    const float* __restrict__ weight,
    const float* __restrict__ bias,
    float*       __restrict__ out)
{
  // double-buffered staging: W 32 KB, X 16 KB; + rank tables 4 KB = 52 KB
  __shared__ __attribute__((aligned(16))) unsigned short WhB[2][2][UHALF][8]; // 16 KB
  __shared__ __attribute__((aligned(16))) unsigned short WlB[2][2][UHALF][8]; // 16 KB
  __shared__ __attribute__((aligned(16))) unsigned short XhB[2][2][MT][8];    //  8 KB
  __shared__ __attribute__((aligned(16))) unsigned short XlB[2][2][MT][8];    //  8 KB
  __shared__ int   sl[BATCH];      // 2 KB raw labels
  __shared__ int   lblr[UHALF];    // 1 KB label value per local rank
  __shared__ float bsubs[UHALF];   // 1 KB bias per local rank

  const int bid = blockIdx.x;
  // XCD-chunked bijective swizzle (392 = 8*49): XCDs 0-3 own uh=0, 4-7 own uh=1,
  // so each XCD's resident W working set is one 512 KB u-half -> L2-hot.
  const int swz = (bid & 7) * (NBLK / 8) + (bid >> 3);
  const int uh  = swz / NMB;
  const int mb  = swz - uh * NMB;

  const int tid  = threadIdx.x;
  const int wave = tid >> 6, lane = tid & 63;
  const int l31  = lane & 31, lq = lane >> 5;

  // ---- rank-select prologue (replaces sort_gather kernel) ----
  {
    const int stride = (labels[1] == 0) ? 2 : 1;  // int64-layout hedge
    const int lt = labels[tid * stride];
    sl[tid] = lt;
    __syncthreads();
    int rank = 0;
#pragma unroll 8
    for (int j = 0; j < BATCH; ++j) rank += (sl[j] < lt) ? 1 : 0;
    const int rloc = rank - uh * UHALF;
    if ((unsigned)rloc < UHALF) { lblr[rloc] = lt; bsubs[rloc] = bias[lt]; }
    __syncthreads();
  }

  // ---- staging duties ----
  // W: thread -> (uloc, kq); loads 32B fp32 of its row per step (kq pair = 64B line)
  const int uloc = tid & 255;
  const int kq   = tid >> 8;
  const float* wp = weight + (size_t)lblr[uloc] * CIN + kq * 8;
  // X: thread -> (mloc, 4 consecutive k)
  const int mloc = tid & 127;
  const int ks   = tid >> 7;            // 0..3
  const int kqs  = ks >> 1;
  const int j0   = (ks & 1) * 4;
  const int mg   = mb * MT + mloc;
  const int bimg = mg / HW;
  const int hwp  = mg - bimg * HW;
  const float* xsrc = x + (size_t)bimg * (CIN * HW) + hwp;

  f32x16 a00 = zero16(), a01 = zero16(), a10 = zero16(), a11 = zero16();
  const int uoff = (wave & 3) * 64;   // wave's u sub-tile within UHALF
  const int moff = (wave >> 2) * 64;  // wave's m sub-tile within MT

  // ---- prologue: stage step 0 into buffer 0 ----
  {
    f32x4 w0 = *(const f32x4*)(wp);
    f32x4 w1 = *(const f32x4*)(wp + 4);
    float xv[4];
#pragma unroll
    for (int i = 0; i < 4; ++i) xv[i] = xsrc[(size_t)(ks * 4 + i) * HW];
    s16x8 ph, pl;
#pragma unroll
    for (int i = 0; i < 4; ++i) {
      unsigned short h, l;
      split2(w0[i], h, l); ph[i] = (short)h;     pl[i] = (short)l;
      split2(w1[i], h, l); ph[4 + i] = (short)h; pl[4 + i] = (short)l;
    }
    *(s16x8*)&WhB[0][kq][uloc][0] = ph;
    *(s16x8*)&WlB[0][kq][uloc][0] = pl;
    s16x4 qh, ql;
#pragma unroll
    for (int i = 0; i < 4; ++i) {
      unsigned short h, l; split2(xv[i], h, l);
      qh[i] = (short)h; ql[i] = (short)l;
    }
    *(s16x4*)&XhB[0][kqs][mloc][j0] = qh;
    *(s16x4*)&XlB[0][kqs][mloc][j0] = ql;
  }
  __syncthreads();

  // ---- main loop: one barrier/step; s+1 global loads issued before MFMA,
  //      split+LDS-write after (T14 issue-early/write-late) ----
  for (int s = 0; s < NSTEP; ++s) {
    const int cur = s & 1, nxt = cur ^ 1;
    const bool pf = (s + 1 < NSTEP);   // block-uniform
    f32x4 w0, w1;
    float xv[4];
    if (pf) {
      const float* wps = wp + (size_t)(s + 1) * KT;
      w0 = *(const f32x4*)(wps);
      w1 = *(const f32x4*)(wps + 4);
      const float* xs = xsrc + (size_t)(s + 1) * KT * HW;
#pragma unroll
      for (int i = 0; i < 4; ++i) xv[i] = xs[(size_t)(ks * 4 + i) * HW];
    }

    bf16x8 ah0 = *(const bf16x8*)&WhB[cur][lq][uoff + l31][0];
    bf16x8 ah1 = *(const bf16x8*)&WhB[cur][lq][uoff + 32 + l31][0];
    bf16x8 al0 = *(const bf16x8*)&WlB[cur][lq][uoff + l31][0];
    bf16x8 al1 = *(const bf16x8*)&WlB[cur][lq][uoff + 32 + l31][0];
    bf16x8 bh0 = *(const bf16x8*)&XhB[cur][lq][moff + l31][0];
    bf16x8 bh1 = *(const bf16x8*)&XhB[cur][lq][moff + 32 + l31][0];
    bf16x8 bl0 = *(const bf16x8*)&XlB[cur][lq][moff + l31][0];
    bf16x8 bl1 = *(const bf16x8*)&XlB[cur][lq][moff + 32 + l31][0];

    // 12 MFMA: 2 u-tiles x 2 m-tiles x 3 split passes (A rows->u, B rows->m)
    a00 = MFMA32(ah0, bh0, a00);  a01 = MFMA32(ah0, bh1, a01);
    a10 = MFMA32(ah1, bh0, a10);  a11 = MFMA32(ah1, bh1, a11);
    a00 = MFMA32(ah0, bl0, a00);  a01 = MFMA32(ah0, bl1, a01);
    a10 = MFMA32(ah1, bl0, a10);  a11 = MFMA32(ah1, bl1, a11);
    a00 = MFMA32(al0, bh0, a00);  a01 = MFMA32(al0, bh1, a01);
    a10 = MFMA32(al1, bh0, a10);  a11 = MFMA32(al1, bh1, a11);

    if (pf) {  // split + stage into nxt (its last readers were step s-1)
      s16x8 ph, pl;
#pragma unroll
      for (int i = 0; i < 4; ++i) {
        unsigned short h, l;
        split2(w0[i], h, l); ph[i] = (short)h;     pl[i] = (short)l;
        split2(w1[i], h, l); ph[4 + i] = (short)h; pl[4 + i] = (short)l;
      }
      *(s16x8*)&WhB[nxt][kq][uloc][0] = ph;
      *(s16x8*)&WlB[nxt][kq][uloc][0] = pl;
      s16x4 qh, ql;
#pragma unroll
      for (int i = 0; i < 4; ++i) {
        unsigned short h, l; split2(xv[i], h, l);
        qh[i] = (short)h; ql[i] = (short)l;
      }
      *(s16x4*)&XhB[nxt][kqs][mloc][j0] = qh;
      *(s16x4*)&XlB[nxt][kqs][mloc][j0] = ql;
    }
    // barrier drains lgkmcnt (LDS writes) — exactly the visibility needed,
    // placed after the MFMA block.
    __syncthreads();
  }

  // ---- epilogue: bias + store (M exact, no masking) ----
  // C/D 32x32: col = lane&31 (m), row = (r&3) + 8*(r>>2) + 4*(lane>>5) (u)
  const int u0g = uh * UHALF + uoff;
  const int m0g = mb * MT + moff;
  const int mA  = m0g + l31,      mB = m0g + 32 + l31;
  const int bA  = mA / HW,        hA = mA - bA * HW;
  const int bB  = mB / HW,        hB = mB - bB * HW;
  float* oA = out + (size_t)bA * (UDIM * HW) + hA;
  float* oB = out + (size_t)bB * (UDIM * HW) + hB;
#pragma unroll
  for (int r = 0; r < 16; ++r) {
    const int urow = (r & 3) + 8 * (r >> 2) + 4 * lq;
    {
      const int ul = uoff + urow;              // local rank index
      const float bs = bsubs[ul];
      const int u = u0g + urow;
      oA[(size_t)u * HW] = a00[r] + bs;
      oB[(size_t)u * HW] = a01[r] + bs;
    }
    {
      const int ul = uoff + 32 + urow;
      const float bs = bsubs[ul];
      const int u = u0g + 32 + urow;
      oA[(size_t)u * HW] = a10[r] + bs;
      oB[(size_t)u * HW] = a11[r] + bs;
    }
  }
}

extern "C" void kernel_launch(void* const* d_in, const int* in_sizes, int n_in,
                              void* d_out, int out_size, void* d_ws, size_t ws_size,
                              hipStream_t stream)
{
  const float* x      = (const float*)d_in[0];
  const int*   labels = (const int*)d_in[1];
  const float* weight = (const float*)d_in[2];
  const float* bias   = (const float*)d_in[3];
  float*       out    = (float*)d_out;

  convcls_fused<<<NBLK, 512, 0, stream>>>(x, labels, weight, bias, out);
}

// Round 15
// 307.076 us; speedup vs baseline: 1.0695x; 1.0695x over previous
//
#include <hip/hip_runtime.h>
#include <hip/hip_bf16.h>

// ConvCls partial-FC 1x1-conv classifier — 2 kernels.
// out[b,u,hw] = sum_c x[b,c,hw] * W[sorted[u], c] + bias[sorted[u]]
// Flattened GEMM: C[m,u], m = b*49+hw, M = 25088 = 64*392 exact.
// fp32 via bf16 hi/lo split, 3 MFMA passes (hh + hl + lh), fp32 accumulate.
// R10 counters: fused 1-kernel variant was latency-bound (MfmaUtil 13.5%,
// VALU 20%, occ 25%): 1.53 blocks/CU imbalance + in-loop W split VALU.
// Fix: pre-split W offline (wprep) + global_load_lds staging + 784-block grid.
#define CIN    512
#define BATCH  512
#define HW     49
#define UDIM   512
#define MTOT   (BATCH * HW)     // 25088
#define MT     64               // m-tile per block
#define NMB    (MTOT / MT)      // 392
#define UHALF  256              // u per block
#define KT     16               // K per pipeline step
#define NSTEP  (CIN / KT)       // 32
#define NBLK   (NMB * 2)        // 784 = 8*98 (bijective XCD swizzle)

typedef short  bf16x8 __attribute__((ext_vector_type(8)));
typedef short  s16x4  __attribute__((ext_vector_type(4)));
typedef float  f32x16 __attribute__((ext_vector_type(16)));

#define MFMA32(A, B, C) __builtin_amdgcn_mfma_f32_32x32x16_bf16((A), (B), (C), 0, 0, 0)

__device__ __forceinline__ void gload_lds16(const void* g, void* l) {
  __builtin_amdgcn_global_load_lds(
      (const __attribute__((address_space(1))) void*)g,
      (__attribute__((address_space(3))) void*)l, 16, 0, 0);
}

// fp32 -> bf16 hi/lo split (RNE via bit trick; finite inputs)
__device__ __forceinline__ void split2(float v, unsigned short& h, unsigned short& l) {
  unsigned int b  = __float_as_uint(v);
  unsigned int hb = (b + 0x7FFFu + ((b >> 16) & 1u)) >> 16;
  float hf        = __uint_as_float(hb << 16);
  unsigned int lb = __float_as_uint(v - hf);
  h = (unsigned short)hb;
  l = (unsigned short)((lb + 0x7FFFu + ((lb >> 16) & 1u)) >> 16);
}

__device__ __forceinline__ f32x16 zero16() {
  f32x16 r;
#pragma unroll
  for (int i = 0; i < 16; ++i) r[i] = 0.f;
  return r;
}

// ---- Kernel 1: rank-select (folded sort) + gather + split W, fragment order -
// layout: W?[ s(32) ][ kq(2) ][ u(512) ][ j(8) ],  k = s*16 + kq*8 + j
__global__ void wprep(const int* __restrict__ labels,
                      const float* __restrict__ weight,
                      const float* __restrict__ bias,
                      unsigned short* __restrict__ whi,
                      unsigned short* __restrict__ wlo,
                      float* __restrict__ bsub)
{
  __shared__ int sl[BATCH];
  __shared__ int myl;
  const int u   = blockIdx.x;
  const int tid = threadIdx.x;  // 256
  const int stride = (labels[1] == 0) ? 2 : 1;  // int64-layout hedge
  sl[tid]       = labels[tid * stride];
  sl[tid + 256] = labels[(tid + 256) * stride];
  __syncthreads();
#pragma unroll
  for (int t = 0; t < 2; ++t) {
    const int lt = sl[tid + t * 256];
    int rank = 0;
#pragma unroll 8
    for (int j = 0; j < BATCH; ++j) rank += (sl[j] < lt) ? 1 : 0;
    if (rank == u) { myl = lt; bsub[u] = bias[lt]; }  // exactly one writer/block
  }
  __syncthreads();
  const int lbl = myl;
  const float* wrow = weight + (size_t)lbl * CIN;
  for (int k = tid; k < CIN; k += 256) {
    unsigned short h, l;
    split2(wrow[k], h, l);
    const int s = k >> 4, kq = (k >> 3) & 1, j = k & 7;
    const size_t idx = (((size_t)(s * 2 + kq)) * UDIM + u) * 8 + j;
    whi[idx] = h;
    wlo[idx] = l;
  }
}

// ---- Kernel 2: main GEMM: 784 blocks x 256 thr, tile 64m x 256u -------------
__global__ __launch_bounds__(256, 4) void convcls_main(
    const float* __restrict__ x,
    const unsigned short* __restrict__ whi,
    const unsigned short* __restrict__ wlo,
    const float* __restrict__ bsub,
    float* __restrict__ out)
{
  // double-buffered: W 16 KB/step (hi+lo), X 4 KB/step -> 40 KB total
  __shared__ __attribute__((aligned(16))) unsigned short WhB[2][2][UHALF][8]; // 16 KB
  __shared__ __attribute__((aligned(16))) unsigned short WlB[2][2][UHALF][8]; // 16 KB
  __shared__ __attribute__((aligned(16))) unsigned short XhB[2][2][MT][8];    //  4 KB
  __shared__ __attribute__((aligned(16))) unsigned short XlB[2][2][MT][8];    //  4 KB

  const int bid = blockIdx.x;
  // XCD-chunked bijective swizzle (784 = 8*98): XCDs 0-3 own uh=0, 4-7 uh=1,
  // so each XCD's W working set is one 512 KB u-half -> L2-hot.
  const int swz = (bid & 7) * (NBLK / 8) + (bid >> 3);
  const int uh  = swz / NMB;
  const int mb  = swz - uh * NMB;

  const int tid  = threadIdx.x;
  const int wave = tid >> 6, lane = tid & 63;
  const int l31  = lane & 31, lq = lane >> 5;

  // X staging duty: thread -> (mloc, 4 consecutive k); coalesced across mloc
  const int mloc = tid & 63;
  const int ks   = tid >> 6;            // 0..3
  const int kqs  = ks >> 1;
  const int j0   = (ks & 1) * 4;
  const int mg   = mb * MT + mloc;
  const int bimg = mg / HW;
  const int hwp  = mg - bimg * HW;
  const float* xsrc = x + (size_t)bimg * (CIN * HW) + hwp;

  // W staging duty: wave handles 4 chunks of 1 KB (16 chunks = 16 KB/step)
  // chunk c: c<8 -> hi, c8=c&7, kqc=c8>>2, qc=c8&3 (u quarter)
  f32x16 a00 = zero16(), a01 = zero16(), a10 = zero16(), a11 = zero16();
  const int uoff = wave * 64;          // wave's u sub-tile within UHALF

  // ---- prologue: stage step 0 into buffer 0 ----
  {
#pragma unroll
    for (int i = 0; i < 4; ++i) {
      const int chunk = wave * 4 + i;
      const bool hi = chunk < 8;
      const int c8 = chunk & 7, kqc = c8 >> 2, qc = c8 & 3;
      const unsigned short* g = (hi ? whi : wlo)
          + (size_t)kqc * (UDIM * 8) + (uh * UHALF + qc * 64) * 8 + lane * 8;
      char* l = (char*)(hi ? &WhB[0][0][0][0] : &WlB[0][0][0][0])
          + kqc * 4096 + qc * 1024;
      gload_lds16(g, l);
    }
    float xv[4];
#pragma unroll
    for (int i = 0; i < 4; ++i) xv[i] = xsrc[(size_t)(ks * 4 + i) * HW];
    s16x4 qh, ql;
#pragma unroll
    for (int i = 0; i < 4; ++i) {
      unsigned short h, l; split2(xv[i], h, l);
      qh[i] = (short)h; ql[i] = (short)l;
    }
    *(s16x4*)&XhB[0][kqs][mloc][j0] = qh;
    *(s16x4*)&XlB[0][kqs][mloc][j0] = ql;
  }
  __syncthreads();

  // ---- main loop: one barrier/step; step s+1 loads overlap MFMA ----
  for (int s = 0; s < NSTEP; ++s) {
    const int cur = s & 1, nxt = cur ^ 1;
    const bool pf = (s + 1 < NSTEP);   // block-uniform
    float xv[4];
    if (pf) {
      const size_t so = (size_t)(s + 1) * (2 * UDIM * 8);
#pragma unroll
      for (int i = 0; i < 4; ++i) {
        const int chunk = wave * 4 + i;
        const bool hi = chunk < 8;
        const int c8 = chunk & 7, kqc = c8 >> 2, qc = c8 & 3;
        const unsigned short* g = (hi ? whi : wlo) + so
            + (size_t)kqc * (UDIM * 8) + (uh * UHALF + qc * 64) * 8 + lane * 8;
        char* l = (char*)(hi ? &WhB[nxt][0][0][0] : &WlB[nxt][0][0][0])
            + kqc * 4096 + qc * 1024;
        gload_lds16(g, l);
      }
      const float* xs = xsrc + (size_t)(s + 1) * KT * HW;
#pragma unroll
      for (int i = 0; i < 4; ++i) xv[i] = xs[(size_t)(ks * 4 + i) * HW];
    }

    bf16x8 ah0 = *(const bf16x8*)&WhB[cur][lq][uoff + l31][0];
    bf16x8 ah1 = *(const bf16x8*)&WhB[cur][lq][uoff + 32 + l31][0];
    bf16x8 al0 = *(const bf16x8*)&WlB[cur][lq][uoff + l31][0];
    bf16x8 al1 = *(const bf16x8*)&WlB[cur][lq][uoff + 32 + l31][0];
    bf16x8 bh0 = *(const bf16x8*)&XhB[cur][lq][l31][0];
    bf16x8 bh1 = *(const bf16x8*)&XhB[cur][lq][32 + l31][0];
    bf16x8 bl0 = *(const bf16x8*)&XlB[cur][lq][l31][0];
    bf16x8 bl1 = *(const bf16x8*)&XlB[cur][lq][32 + l31][0];

    // 12 MFMA: 2 u-tiles x 2 m-tiles x 3 split passes (A rows->u, B rows->m)
    a00 = MFMA32(ah0, bh0, a00);  a01 = MFMA32(ah0, bh1, a01);
    a10 = MFMA32(ah1, bh0, a10);  a11 = MFMA32(ah1, bh1, a11);
    a00 = MFMA32(ah0, bl0, a00);  a01 = MFMA32(ah0, bl1, a01);
    a10 = MFMA32(ah1, bl0, a10);  a11 = MFMA32(ah1, bl1, a11);
    a00 = MFMA32(al0, bh0, a00);  a01 = MFMA32(al0, bh1, a01);
    a10 = MFMA32(al1, bh0, a10);  a11 = MFMA32(al1, bh1, a11);

    if (pf) {  // split + stage next X (nxt buffer; last readers were step s-1)
      s16x4 qh, ql;
#pragma unroll
      for (int i = 0; i < 4; ++i) {
        unsigned short h, l; split2(xv[i], h, l);
        qh[i] = (short)h; ql[i] = (short)l;
      }
      *(s16x4*)&XhB[nxt][kqs][mloc][j0] = qh;
      *(s16x4*)&XlB[nxt][kqs][mloc][j0] = ql;
    }
    // barrier drains vmcnt (W[s+1] gloads) + lgkmcnt (X[s+1] writes): exactly
    // the visibility needed, placed after the MFMA block.
    __syncthreads();
  }

  // ---- epilogue: bias + store (M exact, no masking) ----
  // C/D 32x32: col = lane&31 (m), row = (r&3) + 8*(r>>2) + 4*(lane>>5) (u)
  const int u0g = uh * UHALF + uoff;
  const int m0g = mb * MT;
  const int mA  = m0g + l31,      mB = m0g + 32 + l31;
  const int bA  = mA / HW,        hA = mA - bA * HW;
  const int bB  = mB / HW,        hB = mB - bB * HW;
  float* oA = out + (size_t)bA * (UDIM * HW) + hA;
  float* oB = out + (size_t)bB * (UDIM * HW) + hB;
#pragma unroll
  for (int r = 0; r < 16; ++r) {
    const int urow = (r & 3) + 8 * (r >> 2) + 4 * lq;
    {
      const int u = u0g + urow;
      const float bs = bsub[u];
      oA[(size_t)u * HW] = a00[r] + bs;
      oB[(size_t)u * HW] = a01[r] + bs;
    }
    {
      const int u = u0g + 32 + urow;
      const float bs = bsub[u];
      oA[(size_t)u * HW] = a10[r] + bs;
      oB[(size_t)u * HW] = a11[r] + bs;
    }
  }
}

extern "C" void kernel_launch(void* const* d_in, const int* in_sizes, int n_in,
                              void* d_out, int out_size, void* d_ws, size_t ws_size,
                              hipStream_t stream)
{
  const float* x      = (const float*)d_in[0];
  const int*   labels = (const int*)d_in[1];
  const float* weight = (const float*)d_in[2];
  const float* bias   = (const float*)d_in[3];
  float*       out    = (float*)d_out;

  unsigned short* whi  = (unsigned short*)d_ws;                        // 512 KB
  unsigned short* wlo  = (unsigned short*)((char*)d_ws + 512 * 1024);  // 512 KB
  float*          bsub = (float*)((char*)d_ws + 1024 * 1024);          //   2 KB

  wprep<<<UDIM, 256, 0, stream>>>(labels, weight, bias, whi, wlo, bsub);
  convcls_main<<<NBLK, 256, 0, stream>>>(x, whi, wlo, bsub, out);
}